// Round 4
// baseline (651.803 us; speedup 1.0000x reference)
//
#include <hip/hip_runtime.h>

#define NN 100000
#define NE 1600000
#define DIM 128

typedef __attribute__((ext_vector_type(8))) short short8;
typedef __attribute__((ext_vector_type(4))) float f4;
typedef __attribute__((ext_vector_type(2))) float fl2;

__device__ __forceinline__ unsigned short f2bf(float f){
  unsigned x = __float_as_uint(f);
  x += 0x7fffu + ((x >> 16) & 1u);
  return (unsigned short)(x >> 16);
}
__device__ __forceinline__ float blo(unsigned u){ return __uint_as_float(u << 16); }
__device__ __forceinline__ float bhi(unsigned u){ return __uint_as_float(u & 0xffff0000u); }

// ---------------- fallback sentinel (ws too small diagnostic) ----------------
__global__ void k_sentinel(float* __restrict__ out, int n){
  int i = blockIdx.x * blockDim.x + threadIdx.x;
  if (i < n) out[i] = 12345.0f;
}

// ---------------- CSR build ----------------
__global__ void k_hist(const int* __restrict__ dst, int* __restrict__ cnt){
  int i = blockIdx.x * blockDim.x + threadIdx.x;
  if (i < NE) atomicAdd(&cnt[dst[i]], 1);
}

__global__ void k_bsum(const int* __restrict__ cnt, int* __restrict__ bsum){
  __shared__ int sh[256];
  int t = threadIdx.x, b = blockIdx.x;
  int base = b * 1024 + t * 4;
  int s = 0;
  #pragma unroll
  for (int j = 0; j < 4; ++j){ int i = base + j; if (i < NN) s += cnt[i]; }
  sh[t] = s; __syncthreads();
  for (int off = 128; off > 0; off >>= 1){
    if (t < off) sh[t] += sh[t + off];
    __syncthreads();
  }
  if (t == 0) bsum[b] = sh[0];
}

__global__ void k_scanp(const int* __restrict__ bsum, int* __restrict__ boff){
  __shared__ int sh[128];
  int t = threadIdx.x;
  int v = (t < 98) ? bsum[t] : 0;
  sh[t] = v; __syncthreads();
  for (int off = 1; off < 128; off <<= 1){
    int u = (t >= off) ? sh[t - off] : 0;
    __syncthreads();
    sh[t] += u;
    __syncthreads();
  }
  if (t < 98) boff[t] = sh[t] - v;
}

__global__ void k_scanf(const int* __restrict__ cnt, const int* __restrict__ boff,
                        int* __restrict__ rp, int* __restrict__ pos){
  __shared__ int sh[256];
  int t = threadIdx.x, b = blockIdx.x;
  int base = b * 1024 + t * 4;
  int c[4]; int s = 0;
  #pragma unroll
  for (int j = 0; j < 4; ++j){ int i = base + j; c[j] = (i < NN) ? cnt[i] : 0; s += c[j]; }
  sh[t] = s; __syncthreads();
  int tin = s;
  for (int off = 1; off < 256; off <<= 1){
    int u = (t >= off) ? sh[t - off] : 0;
    __syncthreads();
    sh[t] += u;
    __syncthreads();
  }
  int run = boff[b] + sh[t] - tin;
  #pragma unroll
  for (int j = 0; j < 4; ++j){
    int i = base + j;
    if (i < NN){
      rp[i] = run; pos[i] = run; run += c[j];
      if (i == NN - 1) rp[NN] = run;
    }
  }
}

__global__ void k_scatter(const int* __restrict__ src, const int* __restrict__ dst,
                          int* __restrict__ pos, int* __restrict__ ss){
  int i = blockIdx.x * blockDim.x + threadIdx.x;
  if (i < NE){
    int p = atomicAdd(&pos[dst[i]], 1);
    ss[p] = src[i];
  }
}

// ---------------- W packing: fp32 -> bf16 MFMA B-fragment order ----------------
// [ks 0..7][nb 0..NB16-1][lane 0..63][8 bf16]; B[k][n], n=nb*16+(lane&15),
// k=ks*32+(lane>>4)*8+j; k<128 -> Wl, k>=128 -> Wr.
template<int NB16>
__global__ void k_pack(const float* __restrict__ Wl,
                       const float* __restrict__ Wr,
                       unsigned short* __restrict__ Bp){
  constexpr int DOUT = NB16 * 16;
  int idx = blockIdx.x * blockDim.x + threadIdx.x;
  if (idx >= 8 * NB16 * 64) return;
  int lane = idx & 63;
  int nb = (idx >> 6) % NB16;
  int ks = idx / (64 * NB16);
  int n = nb * 16 + (lane & 15);
  int k0 = ks * 32 + (lane >> 4) * 8;
  short8 v;
  #pragma unroll
  for (int j = 0; j < 8; ++j){
    int k = k0 + j;
    float w = (k < 128) ? Wl[k * DOUT + n] : Wr[(k - 128) * DOUT + n];
    v[j] = (short)f2bf(w);
  }
  ((short8*)Bp)[idx] = v;
}

__device__ __forceinline__ short8 cvt8(f4 a, f4 b){
  short8 r;
  #pragma unroll
  for (int j = 0; j < 4; ++j){ r[j] = (short)f2bf(a[j]); r[j+4] = (short)f2bf(b[j]); }
  return r;
}

// ---------------- fused mean-aggregate + dual-GEMM (+BN+ReLU) ----------------
// Block = 32 rows (N = 3125*32, no tail). Phase 1: 4 waves aggregate 8 rows each
// in fp32, round to bf16x2 in LDS. Phase 2: MFMA 16x16x32 bf16, fp32 accum.
// IN_F32: layer-0 input is fp32 x; else bf16 h. DO_BN: bf16 out (h), else fp32 out.
template<int NB16, bool DO_BN, bool IN_F32>
__global__ __launch_bounds__(256)
void k_fused(const float* __restrict__ Xf, const unsigned* __restrict__ Xb,
             const int* __restrict__ rp, const int* __restrict__ ss,
             const unsigned short* __restrict__ Bp,
             const float* __restrict__ bias,
             const float* __restrict__ bg, const float* __restrict__ bb,
             const float* __restrict__ bm, const float* __restrict__ bv,
             unsigned short* __restrict__ OutB, float* __restrict__ OutF){
  constexpr int DOUT = NB16 * 16;
  constexpr int NBW = NB16 / 4;
  __shared__ unsigned smA[32][68];
  const int t = threadIdx.x;
  const int lane = t & 63;
  const int wv = t >> 6;
  const int m0 = blockIdx.x * 32;

  // ---- phase 1: fp32 mean aggregation -> bf16x2 LDS ----
  for (int rr = 0; rr < 8; ++rr){
    int row = m0 + wv * 8 + rr;
    int beg = rp[row], end = rp[row + 1];
    float ax = 0.f, ay = 0.f;
    int e = beg;
    if constexpr (IN_F32){
      for (; e + 4 <= end; e += 4){
        int s0 = ss[e], s1 = ss[e+1], s2 = ss[e+2], s3 = ss[e+3];
        fl2 v0 = ((const fl2*)(Xf + (size_t)s0 * DIM))[lane];
        fl2 v1 = ((const fl2*)(Xf + (size_t)s1 * DIM))[lane];
        fl2 v2 = ((const fl2*)(Xf + (size_t)s2 * DIM))[lane];
        fl2 v3 = ((const fl2*)(Xf + (size_t)s3 * DIM))[lane];
        ax += v0[0] + v1[0] + v2[0] + v3[0];
        ay += v0[1] + v1[1] + v2[1] + v3[1];
      }
      for (; e < end; ++e){
        fl2 v = ((const fl2*)(Xf + (size_t)ss[e] * DIM))[lane];
        ax += v[0]; ay += v[1];
      }
    } else {
      for (; e + 4 <= end; e += 4){
        int s0 = ss[e], s1 = ss[e+1], s2 = ss[e+2], s3 = ss[e+3];
        unsigned u0 = Xb[s0*64 + lane], u1 = Xb[s1*64 + lane];
        unsigned u2 = Xb[s2*64 + lane], u3 = Xb[s3*64 + lane];
        ax += blo(u0) + blo(u1) + blo(u2) + blo(u3);
        ay += bhi(u0) + bhi(u1) + bhi(u2) + bhi(u3);
      }
      for (; e < end; ++e){
        unsigned u = Xb[ss[e]*64 + lane];
        ax += blo(u); ay += bhi(u);
      }
    }
    int d = end - beg;
    float inv = (d > 0) ? 1.f / (float)d : 0.f;
    ax *= inv; ay *= inv;
    smA[wv*8 + rr][lane] = ((unsigned)f2bf(ay) << 16) | (unsigned)f2bf(ax);
  }
  __syncthreads();

  // ---- phase 2: dual GEMM (K 0..127 = mean@Wl from LDS, 128..255 = h@Wr) ----
  const int q = lane >> 4, lr = lane & 15;
  const short8* pb = (const short8*)Bp + lane;
  f4 acc[2][NBW];
  #pragma unroll
  for (int g = 0; g < 2; ++g)
    #pragma unroll
    for (int j = 0; j < NBW; ++j)
      acc[g][j] = (f4){0.f, 0.f, 0.f, 0.f};

  const unsigned* sA0 = &smA[lr][0];
  const unsigned* sA1 = &smA[lr + 16][0];
  #pragma unroll
  for (int ks = 0; ks < 4; ++ks){
    short8 a0 = *(const short8*)(sA0 + q*4 + ks*16);
    short8 a1 = *(const short8*)(sA1 + q*4 + ks*16);
    #pragma unroll
    for (int j = 0; j < NBW; ++j){
      int nb = wv * NBW + j;
      short8 b = pb[(ks * NB16 + nb) * 64];
      acc[0][j] = __builtin_amdgcn_mfma_f32_16x16x32_bf16(a0, b, acc[0][j], 0, 0, 0);
      acc[1][j] = __builtin_amdgcn_mfma_f32_16x16x32_bf16(a1, b, acc[1][j], 0, 0, 0);
    }
  }
  #pragma unroll
  for (int ks = 0; ks < 4; ++ks){
    short8 a0, a1;
    if constexpr (IN_F32){
      const f4* p0 = (const f4*)(Xf + (size_t)(m0 + lr) * DIM);
      const f4* p1 = (const f4*)(Xf + (size_t)(m0 + lr + 16) * DIM);
      a0 = cvt8(p0[ks*8 + q*2], p0[ks*8 + q*2 + 1]);
      a1 = cvt8(p1[ks*8 + q*2], p1[ks*8 + q*2 + 1]);
    } else {
      a0 = *(const short8*)(Xb + (size_t)(m0 + lr) * 64 + q*4 + ks*16);
      a1 = *(const short8*)(Xb + (size_t)(m0 + lr + 16) * 64 + q*4 + ks*16);
    }
    #pragma unroll
    for (int j = 0; j < NBW; ++j){
      int nb = wv * NBW + j;
      short8 b = pb[((4 + ks) * NB16 + nb) * 64];
      acc[0][j] = __builtin_amdgcn_mfma_f32_16x16x32_bf16(a0, b, acc[0][j], 0, 0, 0);
      acc[1][j] = __builtin_amdgcn_mfma_f32_16x16x32_bf16(a1, b, acc[1][j], 0, 0, 0);
    }
  }

  // ---- epilogue: C/D layout col=lane&15, row=(lane>>4)*4+reg ----
  #pragma unroll
  for (int j = 0; j < NBW; ++j){
    int col = (wv * NBW + j) * 16 + lr;
    float S = 1.f, T;
    if constexpr (DO_BN){
      float s = bg[col] * rsqrtf(bv[col] + 1e-5f);
      S = s;
      T = (bias[col] - bm[col]) * s + bb[col];
    } else {
      T = bias[col];
    }
    #pragma unroll
    for (int r = 0; r < 4; ++r){
      int row = m0 + q * 4 + r;
      float y0 = acc[0][j][r] * S + T;
      float y1 = acc[1][j][r] * S + T;
      if constexpr (DO_BN){
        y0 = y0 > 0.f ? y0 : 0.f;
        y1 = y1 > 0.f ? y1 : 0.f;
        OutB[(size_t)row * DOUT + col] = f2bf(y0);
        OutB[(size_t)(row + 16) * DOUT + col] = f2bf(y1);
      } else {
        OutF[(size_t)row * DOUT + col] = y0;
        OutF[(size_t)(row + 16) * DOUT + col] = y1;
      }
    }
  }
}

extern "C" void kernel_launch(void* const* d_in, const int* in_sizes, int n_in,
                              void* d_out, int out_size, void* d_ws, size_t ws_size,
                              hipStream_t stream){
  const float* x = (const float*)d_in[0];                 // fp32 [N,128]
  const int* ei = (const int*)d_in[1];                    // int32 [2,E]
  const float* Wl0 = (const float*)d_in[2];
  const float* Wr0 = (const float*)d_in[3];
  const float* bl0 = (const float*)d_in[4];
  const float* Wl1 = (const float*)d_in[5];
  const float* Wr1 = (const float*)d_in[6];
  const float* bl1 = (const float*)d_in[7];
  const float* Wl2 = (const float*)d_in[8];
  const float* Wr2 = (const float*)d_in[9];
  const float* bl2 = (const float*)d_in[10];
  const float* g0 = (const float*)d_in[11];
  const float* b0 = (const float*)d_in[12];
  const float* bm0 = (const float*)d_in[13];
  const float* bv0 = (const float*)d_in[14];
  const float* g1 = (const float*)d_in[15];
  const float* b1 = (const float*)d_in[16];
  const float* bm1 = (const float*)d_in[17];
  const float* bv1 = (const float*)d_in[18];

  // ws: rp + ss + bp2 + h1 + h2 = 58,032,896 B (capacity proven in r2/r3 —
  // sentinel never fired). bp2 MUST be in ws: the final k_fused reads it while
  // writing all of d_out (r3's NaN was this race). Remaining d_out scratch
  // (cnt/pos/bsum/boff/bp0/bp1) is consumed strictly before anything writes d_out.
  const size_t REQUIRED = 58032896;
  if (ws_size < REQUIRED){
    k_sentinel<<<(out_size + 255) / 256, 256, 0, stream>>>((float*)d_out, out_size);
    return;
  }

  char* w = (char*)d_ws;
  size_t off = 0;
  auto alloc = [&](size_t bytes) -> char* {
    char* p = w + off; off = (off + bytes + 255) & ~(size_t)255; return p;
  };
  int* rp = (int*)alloc((size_t)(NN + 1) * 4);
  int* ss = (int*)alloc((size_t)NE * 4);
  unsigned short* bp2 = (unsigned short*)alloc(8 * 4 * 64 * 8 * 2);
  unsigned short* h1 = (unsigned short*)alloc((size_t)NN * DIM * 2);
  unsigned short* h2 = (unsigned short*)alloc((size_t)NN * DIM * 2);

  char* ow = (char*)d_out;
  size_t ooff = 0;
  auto oalloc = [&](size_t bytes) -> char* {
    char* p = ow + ooff; ooff = (ooff + bytes + 255) & ~(size_t)255; return p;
  };
  int* cnt  = (int*)oalloc((size_t)NN * 4);
  int* pos  = (int*)oalloc((size_t)NN * 4);
  int* bsum = (int*)oalloc(128 * 4);
  int* boff = (int*)oalloc(128 * 4);
  unsigned short* bp0 = (unsigned short*)oalloc(8 * 8 * 64 * 8 * 2);
  unsigned short* bp1 = (unsigned short*)oalloc(8 * 8 * 64 * 8 * 2);

  const int* srcI = ei;
  const int* dstI = ei + NE;

  hipMemsetAsync(cnt, 0, (size_t)NN * 4, stream);
  k_hist<<<(NE + 255) / 256, 256, 0, stream>>>(dstI, cnt);
  k_bsum<<<98, 256, 0, stream>>>(cnt, bsum);
  k_scanp<<<1, 128, 0, stream>>>(bsum, boff);
  k_scanf<<<98, 256, 0, stream>>>(cnt, boff, rp, pos);
  k_scatter<<<(NE + 255) / 256, 256, 0, stream>>>(srcI, dstI, pos, ss);
  k_pack<8><<<16, 256, 0, stream>>>(Wl0, Wr0, bp0);
  k_pack<8><<<16, 256, 0, stream>>>(Wl1, Wr1, bp1);
  k_pack<4><<<8, 256, 0, stream>>>(Wl2, Wr2, bp2);

  k_fused<8, true, true ><<<3125, 256, 0, stream>>>(x, nullptr, rp, ss, bp0,
      bl0, g0, b0, bm0, bv0, h1, nullptr);
  k_fused<8, true, false><<<3125, 256, 0, stream>>>(nullptr, (const unsigned*)h1, rp, ss, bp1,
      bl1, g1, b1, bm1, bv1, h2, nullptr);
  k_fused<4, false, false><<<3125, 256, 0, stream>>>(nullptr, (const unsigned*)h2, rp, ss, bp2,
      bl2, nullptr, nullptr, nullptr, nullptr, nullptr, (float*)d_out);
}